// Round 10
// baseline (61.714 us; speedup 1.0000x reference)
//
#include <hip/hip_runtime.h>
#include <cstddef>

#define NT 10            // NUM_TOKENS
#define TD 96            // TOKEN_DIM == REF_DIM
#define NH 4             // NUM_HEADS
#define NPOS (32 * 2048) // B*T positions
#define TPB 256
#define LPP 8            // lanes per position
#define XPL 12           // x elems per lane (TD / LPP)

// workspace layout (bytes)
#define WS_WQ 0          // h2    wqH[96][48]   (18432 B) -> staged to LDS in A
#define WS_KV 18432      // float kv[96][12]    ( 4608 B) -> staged to LDS in B
                         //   kv[d][n] = tanh(tanh(tokens[n] . Wk[d])), pad 2
#define WS_WVP 23040     // h2    wvp[6][8][4]  (  768 B) -> staged to LDS in B
                         //   wvp[pp][l][h] = (Wv[h][16pp+l], Wv[h][16pp+8+l])
#define WS_BYTES 23808
#define BLDS (4608 + 768) // Phase B LDS bytes = 5376 (336 float4)

typedef _Float16 h2 __attribute__((ext_vector_type(2)));

__device__ __forceinline__ h2 pack_h2(float a, float b) {
    return __builtin_bit_cast(h2, __builtin_amdgcn_cvt_pkrtz(a, b));
}

__device__ __forceinline__ float fast_tanh(float x) {
    // tanh(x) = 1 - 2/(exp(2x)+1); exact limits at +/-inf, ~1e-6 rel error
    float e = __expf(2.0f * x);
    return 1.0f - 2.0f * __builtin_amdgcn_rcpf(e + 1.0f);
}

__device__ __forceinline__ float dot2acc(h2 a, h2 b, float c) {
#if __has_builtin(__builtin_amdgcn_fdot2)
    return __builtin_amdgcn_fdot2(a, b, c, false);
#else
    c = fmaf((float)a[0], (float)b[0], c);
    return fmaf((float)a[1], (float)b[1], c);
#endif
}

// ---- prep: 48 blocks, block b owns d-slice [2b, 2b+2); block 0 also wvp ----
__global__ __launch_bounds__(256) void gst_prep(
    const float* __restrict__ tokens,
    const float* __restrict__ Wq,
    const float* __restrict__ Wk,
    const float* __restrict__ Wv,
    char* __restrict__ ws)
{
    h2* wqH = (h2*)(ws + WS_WQ);
    float* kv = (float*)(ws + WS_KV);
    h2* wvp = (h2*)(ws + WS_WVP);
    const int b = blockIdx.x;
    const int tid = threadIdx.x;

    // Wq rows -> f16 pairs (2 rows x 48 pairs = 96 work items)
    if (tid < 2 * (TD / 2)) {
        int r = 2 * b + tid / (TD / 2);
        int c = tid % (TD / 2);
        float2 f = ((const float2*)(Wq + r * TD))[c];
        wqH[r * (TD / 2) + c] = pack_h2(f.x, f.y);
    }
    // kv[d][n] = tanh(tanh(tokens[n] . Wk[d]))
    if (tid < 2 * NT) {
        int d = 2 * b + tid / NT;
        int n = tid % NT;
        const float4* tr = (const float4*)(tokens + n * TD);
        const float4* wr = (const float4*)(Wk + d * TD);
        float acc = 0.0f;
        #pragma unroll
        for (int j = 0; j < TD / 4; ++j) {
            float4 a = tr[j];
            float4 w = wr[j];
            acc = fmaf(a.x, w.x, acc);
            acc = fmaf(a.y, w.y, acc);
            acc = fmaf(a.z, w.z, acc);
            acc = fmaf(a.w, w.w, acc);
        }
        kv[d * 12 + n] = fast_tanh(fast_tanh(acc));
    }
    if (tid < 2 * 2) { // zero the pad
        int d = 2 * b + (tid >> 1);
        kv[d * 12 + 10 + (tid & 1)] = 0.0f;
    }
    // wvp pairs (block 0 only): 6*8*4 = 192 items
    if (b == 0 && tid < 192) {
        int pp = tid >> 5;
        int l = (tid >> 2) & 7;
        int h = tid & 3;
        float w1 = Wv[h * TD + 16 * pp + l];
        float w2 = Wv[h * TD + 16 * pp + 8 + l];
        wvp[(pp * 8 + l) * 4 + h] = pack_h2(w1, w2);
    }
}

// ---- Phase A: q projection. tq = tanh(tanh(x @ Wq^T)) stored f16 into the
//      first 192 B of each 384 B output row (out[pos] doubles as tq[pos]). ----
__global__ __launch_bounds__(TPB, 6) void gst_qproj(
    const float* __restrict__ ref_emb,
    const char* __restrict__ ws,
    float* __restrict__ out)
{
    __shared__ __align__(16) h2 wqS[TD * (TD / 2)]; // 18432 B

    const int tid = threadIdx.x;
    const int pos = (blockIdx.x * TPB + tid) >> 3;
    const int l = tid & 7;

    const float4* xr = (const float4*)(ref_emb + (size_t)pos * TD + l * XPL);
    float4 x0 = xr[0], x1 = xr[1], x2 = xr[2];

    { // stage wq -> LDS (1152 float4)
        const float4* src = (const float4*)ws;
        float4* dst = (float4*)wqS;
        #pragma unroll
        for (int i = 0; i < 4; ++i)
            dst[tid + i * TPB] = src[tid + i * TPB];
        if (tid < 128) dst[tid + 4 * TPB] = src[tid + 4 * TPB];
    }

    h2 xh[6];
    xh[0] = pack_h2(x0.x, x0.y); xh[1] = pack_h2(x0.z, x0.w);
    xh[2] = pack_h2(x1.x, x1.y); xh[3] = pack_h2(x1.z, x1.w);
    xh[4] = pack_h2(x2.x, x2.y); xh[5] = pack_h2(x2.z, x2.w);
    __syncthreads();

    _Float16* tqp = (_Float16*)(out + (size_t)pos * TD);

    #pragma unroll 2
    for (int cc = 0; cc < 12; ++cc) {
        float p[8];
        #pragma unroll
        for (int i = 0; i < 8; ++i) {
            const h2* w = &wqS[(8 * cc + (l ^ i)) * (TD / 2) + l * (XPL / 2)];
            float a = 0.0f;
            #pragma unroll
            for (int j = 0; j < XPL / 2; ++j) a = dot2acc(xh[j], w[j], a);
            p[i] = a;
        }
        // select-free xor butterfly (p[i] holds row l^i)
        p[0] += __shfl_xor(p[1], 1);
        p[2] += __shfl_xor(p[3], 1);
        p[4] += __shfl_xor(p[5], 1);
        p[6] += __shfl_xor(p[7], 1);
        p[0] += __shfl_xor(p[2], 2);
        p[4] += __shfl_xor(p[6], 2);
        p[0] += __shfl_xor(p[4], 4);

        tqp[8 * cc + l] = (_Float16)fast_tanh(fast_tanh(p[0]));
    }
}

// ---- Phase B: s-phase + softmax + style. Reads tq f16 from its own out row
//      (safe: reads precede writes in the same wave's program order and all
//      outputs data-depend on all tq loads), then overwrites the row. ----
__global__ __launch_bounds__(TPB, 6) void gst_attn(
    const float* __restrict__ tokens,
    const char* __restrict__ ws,
    float* __restrict__ out)
{
    __shared__ __align__(16) char lds[BLDS]; // kv 4608 | wvp 768
    const float* kvS = (const float*)lds;
    const h2* wvpS = (const h2*)(lds + 4608);

    const int tid = threadIdx.x;
    const int pos = (blockIdx.x * TPB + tid) >> 3;
    const int l = tid & 7;

    { // stage kv+wvp -> LDS (336 float4)
        const float4* src = (const float4*)(ws + WS_KV);
        float4* dst = (float4*)lds;
        dst[tid] = src[tid];
        if (tid < 80) dst[256 + tid] = src[256 + tid];
    }

    // load this lane's 12 tq values (f16, from its own output row)
    const _Float16* tqp = (const _Float16*)(out + (size_t)pos * TD);
    float tq[12];
    #pragma unroll
    for (int cc = 0; cc < 12; ++cc) tq[cc] = (float)tqp[8 * cc + l];
    __syncthreads();

    float logits[NT][NH];
    #pragma unroll
    for (int n = 0; n < NT; ++n)
        #pragma unroll
        for (int h = 0; h < NH; ++h) logits[n][h] = 0.0f;

    // ---- s-phase over 6 d-pairs: d1 = 16pp+l, d2 = d1+8 ----
    #pragma unroll
    for (int pp = 0; pp < 6; ++pp) {
        const int d1 = 16 * pp + l;
        const float t1 = tq[2 * pp], t2 = tq[2 * pp + 1];

        const float4 ka1 = *(const float4*)&kvS[d1 * 12];
        const float4 kb1 = *(const float4*)&kvS[d1 * 12 + 4];
        const float2 kc1 = *(const float2*)&kvS[d1 * 12 + 8];
        const float4 ka2 = *(const float4*)&kvS[(d1 + 8) * 12];
        const float4 kb2 = *(const float4*)&kvS[(d1 + 8) * 12 + 4];
        const float2 kc2 = *(const float2*)&kvS[(d1 + 8) * 12 + 8];
        const float kv1[NT] = {ka1.x, ka1.y, ka1.z, ka1.w, kb1.x, kb1.y, kb1.z, kb1.w, kc1.x, kc1.y};
        const float kv2[NT] = {ka2.x, ka2.y, ka2.z, ka2.w, kb2.x, kb2.y, kb2.z, kb2.w, kc2.x, kc2.y};

        const h2* wrow = &wvpS[(pp * 8 + l) * 4];
        const h2 w0 = wrow[0], w1 = wrow[1], w2 = wrow[2], w3 = wrow[3];

        #pragma unroll
        for (int n = 0; n < NT; ++n) {
            // s = tanh(q + k) via addition formula on pre-tanh'd values
            float s1 = (t1 + kv1[n]) * __builtin_amdgcn_rcpf(fmaf(t1, kv1[n], 1.0f));
            float s2 = (t2 + kv2[n]) * __builtin_amdgcn_rcpf(fmaf(t2, kv2[n], 1.0f));
            h2 sp = pack_h2(s1, s2);
            logits[n][0] = dot2acc(sp, w0, logits[n][0]);
            logits[n][1] = dot2acc(sp, w1, logits[n][1]);
            logits[n][2] = dot2acc(sp, w2, logits[n][2]);
            logits[n][3] = dot2acc(sp, w3, logits[n][3]);
        }
    }

    // ---- logits reduce-scatter: lane ends with lh[n] for head h = l&3 ----
    const bool myb0 = (l & 1) != 0;
    const bool myb1 = (l & 2) != 0;
    float lh[NT];
    #pragma unroll
    for (int n = 0; n < NT; ++n) {
        float L0 = logits[n][0], L1 = logits[n][1];
        float L2 = logits[n][2], L3 = logits[n][3];
        L0 += __shfl_xor(L0, 4);
        L1 += __shfl_xor(L1, 4);
        L2 += __shfl_xor(L2, 4);
        L3 += __shfl_xor(L3, 4);
        float m0 = myb1 ? L2 : L0, m1 = myb1 ? L3 : L1;
        float t0 = myb1 ? L0 : L2, t1 = myb1 ? L1 : L3;
        m0 += __shfl_xor(t0, 2);
        m1 += __shfl_xor(t1, 2);
        float mm = myb0 ? m1 : m0, tt = myb0 ? m0 : m1;
        lh[n] = mm + __shfl_xor(tt, 1);
    }

    // ---- per-lane softmax (head l&3); wn[n] = mean_h attn ----
    float m = lh[0];
    #pragma unroll
    for (int n = 1; n < NT; ++n) m = fmaxf(m, lh[n]);
    float e[NT];
    float ssum = 0.0f;
    #pragma unroll
    for (int n = 0; n < NT; ++n) {
        e[n] = __expf(lh[n] - m);
        ssum += e[n];
    }
    const float inv = 0.25f * __builtin_amdgcn_rcpf(ssum);
    float wn[NT];
    #pragma unroll
    for (int n = 0; n < NT; ++n) {
        float v = e[n] * inv;
        v += __shfl_xor(v, 1);
        v += __shfl_xor(v, 2);
        wn[n] = v;
    }

    // ---- style + coalesced store ----
    float4* ob = (float4*)(out + (size_t)pos * TD);
    const float4* t4 = (const float4*)tokens;
    #pragma unroll
    for (int jj = 0; jj < 3; ++jj) {
        const int d4 = l + 8 * jj;
        float4 o = make_float4(0.f, 0.f, 0.f, 0.f);
        #pragma unroll
        for (int n = 0; n < NT; ++n) {
            float4 t = t4[n * (TD / 4) + d4];
            o.x = fmaf(wn[n], t.x, o.x);
            o.y = fmaf(wn[n], t.y, o.y);
            o.z = fmaf(wn[n], t.z, o.z);
            o.w = fmaf(wn[n], t.w, o.w);
        }
        ob[d4] = o;
    }
}

extern "C" void kernel_launch(void* const* d_in, const int* in_sizes, int n_in,
                              void* d_out, int out_size, void* d_ws, size_t ws_size,
                              hipStream_t stream) {
    const float* ref_emb = (const float*)d_in[0];
    const float* tokens  = (const float*)d_in[1];
    const float* Wq      = (const float*)d_in[2];
    const float* Wk      = (const float*)d_in[3];
    const float* Wv      = (const float*)d_in[4];
    float* out = (float*)d_out;

    gst_prep<<<TD / 2, 256, 0, stream>>>(tokens, Wq, Wk, Wv, (char*)d_ws);
    gst_qproj<<<(NPOS * LPP) / TPB, TPB, 0, stream>>>(ref_emb, (const char*)d_ws, out);
    gst_attn<<<(NPOS * LPP) / TPB, TPB, 0, stream>>>(tokens, (const char*)d_ws, out);
}

// Round 14
// 54.000 us; speedup vs baseline: 1.1429x; 1.1429x over previous
//
#include <hip/hip_runtime.h>
#include <cstddef>

#define NT 10            // NUM_TOKENS
#define TD 96            // TOKEN_DIM == REF_DIM
#define NH 4             // NUM_HEADS
#define NPOS (32 * 2048) // B*T positions
#define TPB 256
#define LPP 8            // lanes per position
#define XPL 12           // x elems per lane (TD / LPP)

// workspace layout (bytes)
// wq2: swizzled Wq f16: [cc=12][i=8][l=8][8 h2] (6 used + 2 pad) = 24576 B.
//   element (cc,i,l,m) = pack(Wq[8cc+(l^i)][l*12+2m], Wq[8cc+(l^i)][l*12+2m+1])
#define WS_WQ2 0
#define WS_KVW 24576     // float kvw[96][16]: row d = [wv0..3 | kv0..9 | pad2] (6144 B)
#define WS_BYTES 30720

typedef _Float16 h2 __attribute__((ext_vector_type(2)));

__device__ __forceinline__ h2 pack_h2(float a, float b) {
    return __builtin_bit_cast(h2, __builtin_amdgcn_cvt_pkrtz(a, b));
}

__device__ __forceinline__ float fast_tanh(float x) {
    // tanh(x) = 1 - 2/(exp(2x)+1); exact limits at +/-inf, ~1e-6 rel error
    float e = __expf(2.0f * x);
    return 1.0f - 2.0f * __builtin_amdgcn_rcpf(e + 1.0f);
}

__device__ __forceinline__ float dot2acc(h2 a, h2 b, float c) {
#if __has_builtin(__builtin_amdgcn_fdot2)
    return __builtin_amdgcn_fdot2(a, b, c, false);
#else
    c = fmaf((float)a[0], (float)b[0], c);
    return fmaf((float)a[1], (float)b[1], c);
#endif
}

// ---- prep: 48 blocks; block b: 128 swizzled wq h2 + d-slice [2b,2b+2) of kvw --
__global__ __launch_bounds__(256) void gst_prep(
    const float* __restrict__ tokens,
    const float* __restrict__ Wq,
    const float* __restrict__ Wk,
    const float* __restrict__ Wv,
    char* __restrict__ ws)
{
    h2* wq2 = (h2*)(ws + WS_WQ2);
    float* kvw = (float*)(ws + WS_KVW);
    const int b = blockIdx.x;
    const int tid = threadIdx.x;

    // swizzled Wq: 6144 h2 total = 48 blocks x 128
    if (tid < 128) {
        int o = b * 128 + tid;
        int m = o & 7;
        int l = (o >> 3) & 7;
        int i = (o >> 6) & 7;
        int cc = o >> 9;
        int row = 8 * cc + (l ^ i);
        h2 v = pack_h2(0.0f, 0.0f);
        if (m < 6) {
            int c0 = l * XPL + 2 * m;
            v = pack_h2(Wq[row * TD + c0], Wq[row * TD + c0 + 1]);
        }
        wq2[o] = v;
    }
    // kvw[d][4+n] = tanh(tanh(tokens[n] . Wk[d]))  (pre-tanh'd, addition formula)
    if (tid < 2 * NT) {
        int d = 2 * b + tid / NT;
        int n = tid % NT;
        const float4* tr = (const float4*)(tokens + n * TD);
        const float4* wr = (const float4*)(Wk + d * TD);
        float acc = 0.0f;
        #pragma unroll
        for (int j = 0; j < TD / 4; ++j) {
            float4 a = tr[j];
            float4 w = wr[j];
            acc = fmaf(a.x, w.x, acc);
            acc = fmaf(a.y, w.y, acc);
            acc = fmaf(a.z, w.z, acc);
            acc = fmaf(a.w, w.w, acc);
        }
        kvw[d * 16 + 4 + n] = fast_tanh(fast_tanh(acc));
    }
    // kvw[d][h] = Wv[h][d]; zero pad
    if (tid < 2 * NH) {
        int d = 2 * b + (tid >> 2);
        int h = tid & 3;
        kvw[d * 16 + h] = Wv[h * TD + d];
    }
    if (tid < 2 * 2) {
        int d = 2 * b + (tid >> 1);
        kvw[d * 16 + 14 + (tid & 1)] = 0.0f;
    }
}

// ---- main: 8 lanes/pos; q-phase reads swizzled wq via b128+b64 (2 DS ops
//      per row-part instead of 6 scalar b32 — the R9 DS-pipe bottleneck) ----
__global__ __launch_bounds__(TPB, 6) void gst_main(
    const float* __restrict__ ref_emb,
    const float* __restrict__ tokens,
    const char* __restrict__ ws,
    float* __restrict__ out)
{
    __shared__ __align__(16) h2 wq2S[12 * 8 * 8 * 8]; // 24576 B

    const int tid = threadIdx.x;
    const int pos = (blockIdx.x * TPB + tid) >> 3;
    const int l = tid & 7;
    const float* kvw = (const float*)(ws + WS_KVW); // L1-resident 6 KB table

    // prefetch this lane's x twelfth (3 float4), overlapping the LDS copy
    const float4* xr = (const float4*)(ref_emb + (size_t)pos * TD + l * XPL);
    float4 x0 = xr[0], x1 = xr[1], x2 = xr[2];

    // stage swizzled wq -> LDS: 1536 float4, 6 per thread
    {
        const float4* src = (const float4*)ws;
        float4* dst = (float4*)wq2S;
        #pragma unroll
        for (int i = 0; i < 6; ++i)
            dst[tid + i * TPB] = src[tid + i * TPB];
    }

    h2 xh[6];
    xh[0] = pack_h2(x0.x, x0.y); xh[1] = pack_h2(x0.z, x0.w);
    xh[2] = pack_h2(x1.x, x1.y); xh[3] = pack_h2(x1.z, x1.w);
    xh[4] = pack_h2(x2.x, x2.y); xh[5] = pack_h2(x2.z, x2.w);
    __syncthreads();

    float logits[NT][NH];
    #pragma unroll
    for (int n = 0; n < NT; ++n)
        #pragma unroll
        for (int h = 0; h < NH; ++h) logits[n][h] = 0.0f;

    union U4 { float4 f; h2 h[4]; };
    union U2 { float2 f; h2 h[2]; };

    // ---- fused q + s phase: 12 groups of 8 d's ----
    #pragma unroll 2
    for (int cc = 0; cc < 12; ++cc) {
        // partial dots, row-relative: p[i] = partial of row (8cc + (l^i))
        float p[8];
        #pragma unroll
        for (int i = 0; i < 8; ++i) {
            const h2* wp = wq2S + (((cc * 8 + i) * 8) + l) * 8;
            U4 a; a.f = *(const float4*)wp;       // h2 0..3 (16B, one b128)
            U2 b; b.f = *(const float2*)(wp + 4); // h2 4..5 ( 8B, one b64)
            float acc = 0.0f;
            acc = dot2acc(xh[0], a.h[0], acc);
            acc = dot2acc(xh[1], a.h[1], acc);
            acc = dot2acc(xh[2], a.h[2], acc);
            acc = dot2acc(xh[3], a.h[3], acc);
            acc = dot2acc(xh[4], b.h[0], acc);
            acc = dot2acc(xh[5], b.h[1], acc);
            p[i] = acc;
        }
        // select-free xor butterfly: p[i] holds row l^i -> partner has it at i^m
        p[0] += __shfl_xor(p[1], 1);
        p[2] += __shfl_xor(p[3], 1);
        p[4] += __shfl_xor(p[5], 1);
        p[6] += __shfl_xor(p[7], 1);
        p[0] += __shfl_xor(p[2], 2);
        p[4] += __shfl_xor(p[6], 2);
        p[0] += __shfl_xor(p[4], 4);

        // tq = tanh(q), q = tanh(raw)   (for the exact tanh addition formula)
        const float tq = fast_tanh(fast_tanh(p[0]));

        // s phase for d = 8*cc + l: s = (tq + tk)/(1 + tq*tk) = tanh(q + k)
        const int d = 8 * cc + l;
        const float* row = kvw + d * 16;
        const float4 wv = *(const float4*)(row);      // wv0..3
        const float4 ka = *(const float4*)(row + 4);  // kv0..3
        const float4 kb = *(const float4*)(row + 8);  // kv4..7
        const float2 kc = *(const float2*)(row + 12); // kv8..9
        const float kv[NT] = {ka.x, ka.y, ka.z, ka.w, kb.x, kb.y, kb.z, kb.w, kc.x, kc.y};
        #pragma unroll
        for (int n = 0; n < NT; ++n) {
            float num = tq + kv[n];
            float den = fmaf(tq, kv[n], 1.0f);
            float s = num * __builtin_amdgcn_rcpf(den);
            logits[n][0] = fmaf(s, wv.x, logits[n][0]);
            logits[n][1] = fmaf(s, wv.y, logits[n][1]);
            logits[n][2] = fmaf(s, wv.z, logits[n][2]);
            logits[n][3] = fmaf(s, wv.w, logits[n][3]);
        }
    }

    // ---- logits reduce-scatter over the 8-lane group:
    //      lane ends with lh[n] = fully-reduced logits[n][h = l&3] ----
    const bool myb0 = (l & 1) != 0;
    const bool myb1 = (l & 2) != 0;
    float lh[NT];
    #pragma unroll
    for (int n = 0; n < NT; ++n) {
        float L0 = logits[n][0], L1 = logits[n][1];
        float L2 = logits[n][2], L3 = logits[n][3];
        L0 += __shfl_xor(L0, 4);
        L1 += __shfl_xor(L1, 4);
        L2 += __shfl_xor(L2, 4);
        L3 += __shfl_xor(L3, 4);
        float m0 = myb1 ? L2 : L0, m1 = myb1 ? L3 : L1;
        float t0 = myb1 ? L0 : L2, t1 = myb1 ? L1 : L3;
        m0 += __shfl_xor(t0, 2);
        m1 += __shfl_xor(t1, 2);
        float mm = myb0 ? m1 : m0, tt = myb0 ? m0 : m1;
        lh[n] = mm + __shfl_xor(tt, 1);
    }

    // ---- per-lane softmax for head h=l&3; then wn[n] = mean_h attn ----
    float m = lh[0];
    #pragma unroll
    for (int n = 1; n < NT; ++n) m = fmaxf(m, lh[n]);
    float e[NT];
    float ssum = 0.0f;
    #pragma unroll
    for (int n = 0; n < NT; ++n) {
        e[n] = __expf(lh[n] - m);
        ssum += e[n];
    }
    const float inv = 0.25f * __builtin_amdgcn_rcpf(ssum);
    float wn[NT];
    #pragma unroll
    for (int n = 0; n < NT; ++n) {
        float v = e[n] * inv;      // 0.25 * attn[n][l&3]
        v += __shfl_xor(v, 1);     // sum heads differing in bit0
        v += __shfl_xor(v, 2);     // sum heads differing in bit1
        wn[n] = v;                 // mean_h attn[n][h], replicated
    }

    // ---- style + store, coalesced: lane handles float4-index l + 8*jj ----
    float4* ob = (float4*)(out + (size_t)pos * TD);
    const float4* t4 = (const float4*)tokens;
    #pragma unroll
    for (int jj = 0; jj < 3; ++jj) {
        const int d4 = l + 8 * jj;
        float4 o = make_float4(0.f, 0.f, 0.f, 0.f);
        #pragma unroll
        for (int n = 0; n < NT; ++n) {
            float4 t = t4[n * (TD / 4) + d4];
            o.x = fmaf(wn[n], t.x, o.x);
            o.y = fmaf(wn[n], t.y, o.y);
            o.z = fmaf(wn[n], t.z, o.z);
            o.w = fmaf(wn[n], t.w, o.w);
        }
        ob[d4] = o;
    }
}

extern "C" void kernel_launch(void* const* d_in, const int* in_sizes, int n_in,
                              void* d_out, int out_size, void* d_ws, size_t ws_size,
                              hipStream_t stream) {
    const float* ref_emb = (const float*)d_in[0];
    const float* tokens  = (const float*)d_in[1];
    const float* Wq      = (const float*)d_in[2];
    const float* Wk      = (const float*)d_in[3];
    const float* Wv      = (const float*)d_in[4];
    float* out = (float*)d_out;

    gst_prep<<<48, 256, 0, stream>>>(tokens, Wq, Wk, Wv, (char*)d_ws);
    gst_main<<<(NPOS * LPP) / TPB, TPB, 0, stream>>>(ref_emb, tokens,
                                                     (const char*)d_ws, out);
}